// Round 1
// baseline (228.708 us; speedup 1.0000x reference)
//
#include <hip/hip_runtime.h>

// Problem constants (match reference)
#define B_DIM   64
#define M_DIM   128
#define F_HALF  32      // F1 == F2 == 32
#define K_DIM   64      // F1 + F2
#define NFILT   32      // FILTERS
#define ROWS    (B_DIM * M_DIM)     // 8192 output rows
#define WPB     4                   // waves (=rows) per block
#define NBLK    (ROWS / WPB)        // 2048 blocks = 8 blocks/CU * 256 CU (one generation)

__device__ __forceinline__ float readlane_f(float v, int l) {
    return __uint_as_float(__builtin_amdgcn_readlane(__float_as_uint(v), l));
}

// Gather up to 8 masked neighbor feature values (this lane's feature column)
// and FMA into acc. All 8 loads issue back-to-back (branchless, clamped index)
// so a typical half-row (~6.4 neighbors) costs ONE memory round-trip.
__device__ __forceinline__ void gather8(unsigned long long& m,
                                        const float* __restrict__ bb,
                                        float av, float& acc)
{
    int j[8];
    #pragma unroll
    for (int u = 0; u < 8; ++u) {
        j[u] = m ? (int)__builtin_ctzll(m) : -1;
        m &= (m - 1);                       // no-op when m == 0
    }
    float v[8], s[8];
    #pragma unroll
    for (int u = 0; u < 8; ++u) {
        int jj = j[u] < 0 ? 0 : j[u];       // clamp keeps address in-bounds
        v[u] = bb[(size_t)jj * F_HALF];     // 8 independent loads in flight
    }
    #pragma unroll
    for (int u = 0; u < 8; ++u) {
        int jj = j[u] < 0 ? 0 : j[u];
        float a = readlane_f(av, jj);       // uniform index -> scalar broadcast
        s[u] = (j[u] >= 0) ? a : 0.0f;      // invalid slots contribute 0
    }
    #pragma unroll
    for (int u = 0; u < 8; ++u)
        acc = fmaf(s[u], v[u], acc);
}

// One WAVE per output row (b,i). No block barriers in the main path.
// out[b,i,f] = sum_k ( sum_j adj[b,i,j]*x[b,i,j,k] ) * W[k,f] + deg[b,i]*bias[f]
__global__ __launch_bounds__(256, 8)
void gconv_kernel(const float* __restrict__ sf1,
                  const float* __restrict__ sf2,
                  const float* __restrict__ adj,
                  const float* __restrict__ W,
                  const float* __restrict__ bias,
                  float* __restrict__ out)
{
    __shared__ float s_W[K_DIM * NFILT];    // 8 KB, shared by the 4 waves
    __shared__ float s_y[WPB][K_DIM];       // per-wave pooled features

    const int t    = threadIdx.x;
    const int w    = t >> 6;                // wave 0..3
    const int lane = t & 63;
    const int row  = blockIdx.x * WPB + w;  // b*M + i

    // --- issue the long-latency loads first -------------------------------
    const float* adj_row = adj + (size_t)row * M_DIM;
    float a_lo = adj_row[lane];             // adjacency row -> registers
    float a_hi = adj_row[lane + 64];
    float bf   = bias[lane & (NFILT - 1)];  // bias prefetch

    // cooperative W preload (512 float4 / 256 threads = 2 each, coalesced)
    {
        float4*       s_W4 = reinterpret_cast<float4*>(s_W);
        const float4* W4   = reinterpret_cast<const float4*>(W);
        s_W4[t]       = W4[t];
        s_W4[t + 256] = W4[t + 256];
    }
    __syncthreads();                        // only block-wide barrier (s_W)

    // feature base: lanes 0..31 -> sf1 feature lane, lanes 32..63 -> sf2
    const size_t row_base = (size_t)row * (M_DIM * F_HALF);
    const float* base = (lane < F_HALF)
                          ? (sf1 + row_base + lane)
                          : (sf2 + row_base + (lane - F_HALF));

    // --- in-register compaction: ballot masks of nonzero adjacency --------
    unsigned long long m_lo = __ballot(a_lo != 0.0f);
    unsigned long long m_hi = __ballot(a_hi != 0.0f);

    float acc = 0.0f;
    {
        unsigned long long m = m_lo;
        while (m) gather8(m, base, a_lo, acc);
    }
    {
        unsigned long long m = m_hi;
        const float* bb = base + (size_t)64 * F_HALF;
        while (m) gather8(m, bb, a_hi, acc);
    }

    // degree = sum_j adj[b,i,j] (full-wave butterfly reduce, all lanes get it)
    float d = a_lo + a_hi;
    #pragma unroll
    for (int off = 32; off; off >>= 1)
        d += __shfl_xor(d, off);

    // --- per-wave GEMV: out[f] = deg*bias[f] + sum_k y[k]*W[k,f] ----------
    s_y[w][lane] = acc;
    asm volatile("s_waitcnt lgkmcnt(0)" ::: "memory");  // wave-local LDS fence
    __builtin_amdgcn_wave_barrier();

    const int f     = lane & 31;            // output filter
    const int halfk = lane >> 5;            // k-range split across lane halves
    float o = 0.0f;
    #pragma unroll
    for (int kk = 0; kk < 32; ++kk) {
        const int k = halfk * 32 + kk;
        // s_y: 2 broadcast addresses (2-way = free); s_W: stride-1, conflict-free
        o = fmaf(s_y[w][k], s_W[k * NFILT + f], o);
    }
    o += __shfl_down(o, 32);                // combine the two k-halves

    if (lane < NFILT)
        out[(size_t)row * NFILT + lane] = fmaf(d, bf, o);
}

extern "C" void kernel_launch(void* const* d_in, const int* in_sizes, int n_in,
                              void* d_out, int out_size, void* d_ws, size_t ws_size,
                              hipStream_t stream) {
    const float* sf1  = (const float*)d_in[0];
    const float* sf2  = (const float*)d_in[1];
    const float* adj  = (const float*)d_in[2];
    const float* W    = (const float*)d_in[3];
    const float* bias = (const float*)d_in[4];
    float* out = (float*)d_out;

    gconv_kernel<<<NBLK, 256, 0, stream>>>(sf1, sf2, adj, W, bias, out);
}